// Round 1
// baseline (1263.875 us; speedup 1.0000x reference)
//
#include <hip/hip_runtime.h>

// x:   (2,4,8,8,8,96,96) fp32   strides: b 18874368, ci 4718592, cd 589824, t 73728, d 9216, h 96, w 1
// W:   (9,4,4,3,3,3)     fp32   strides: ij 432, o 108, ci 27, kd 9, kh 3, kw 1
// b:   (9,4)             fp32
// out: (2,4,6,6,8,96,96) fp32
//
// Round-1 changes vs baseline (853 us):
//  - weights moved OUT of LDS: repacked once into workspace by prep_kernel
//    ([ci][ij][kd][kh][kw][o] + mean-bias at [3888..3891]); main loop reads
//    them with wave-uniform addresses -> s_load/L1 broadcast. LDS 38.4->22.7KB
//    so occupancy rises from ~3.2 to ~5 blocks/CU.
//  - LDS row stride 104 -> 105 (odd): compute-read banks split across both
//    parities -> 2 lanes/bank (free) instead of structural 4-way conflict.
//    Staging writes become 4x ds_write_b32 (105 breaks 16B alignment).
//  - T14 async staging: per-thread staging descriptors are loop-invariant
//    (precomputed once); each iter issues next tile's global_load_dwordx4
//    into regs BEFORE the 648 FMAs, LDS-writes them after the next barrier.
//    Invalid halo rows zeroed once, never re-staged.

#define BLOCK 256
#define XSTRIDE 105   // odd stride: 105 mod 32 = 9 -> adjacent rows alternate bank parity

__global__ void prep_kernel(const float* __restrict__ Wg,
                            const float* __restrict__ bg,
                            float* __restrict__ ws)
{
    int k = blockIdx.x * blockDim.x + threadIdx.x;
    if (k < 3888) {
        int o  = k & 3;  int r = k >> 2;
        int kw = r % 3;  r /= 3;
        int kh = r % 3;  r /= 3;
        int kd = r % 3;  r /= 3;
        int ij = r % 9;  int ci = r / 9;
        ws[k] = Wg[ij*432 + o*108 + ci*27 + kd*9 + kh*3 + kw];
    }
    if (k < 4) {
        float s = 0.f;
        #pragma unroll
        for (int ij = 0; ij < 9; ++ij) s += bg[ij*4 + k];
        ws[3888 + k] = s * (1.0f / 9.0f);
    }
}

__global__ __launch_bounds__(256, 5) void conv5d_kernel(
    const float* __restrict__ xg,
    const float* __restrict__ wsW,
    float* __restrict__ outg)
{
    __shared__ float xs[54 * XSTRIDE];   // [pl(3)][hr(18)][wcol(105)], 22680 B

    // zero everything once: covers w-halo cols (3 and 100) and invalid
    // (out-of-range d/h) rows, which are never re-staged afterwards.
    for (int k = threadIdx.x; k < 54 * XSTRIDE; k += BLOCK) xs[k] = 0.f;

    // Block decode with XCD-aware swizzle (unchanged): 3456 blocks =
    // 72 (b,c,t) slabs x 48 (d,ht); each XCD gets 9 contiguous slabs.
    int bi   = blockIdx.x;
    int xcd  = bi & 7;
    int g    = bi >> 3;
    int slab = xcd*9 + g/48;
    int r2   = g % 48;
    int d    = r2 / 6;
    int ht   = r2 % 6;
    int b    = slab / 36;
    int ct   = slab % 36;
    int c    = ct / 6;
    int t    = ct % 6;
    int h0   = ht * 16;

    int wt     = threadIdx.x & 15;   // w tile: w0 = 6*wt
    int hr_out = threadIdx.x >> 4;   // 0..15

    // ---- precompute loop-invariant staging descriptors (6 passes/thread) ----
    int  goff[6];   // float offset within the (ci, c+i, t+j) plane-slab
    int  lw[6];     // LDS word index of first of 4 writes
    bool pv[6];     // this pass writes a valid row
    #pragma unroll
    for (int p = 0; p < 6; ++p) {
        int u   = threadIdx.x + p*BLOCK;   // 0..1535, valid < 1296
        int row = u / 24;                  // 0..53 (may exceed for p=5; masked)
        int q   = u % 24;
        int pl  = row / 18;
        int hr  = row % 18;
        int dd  = d + pl - 1;
        int hh  = h0 + hr - 1;
        pv[p]   = (u < 1296) && ((unsigned)dd < 8u) && ((unsigned)hh < 96u);
        goff[p] = dd*9216 + hh*96 + q*4;   // garbage if !pv -> never used
        lw[p]   = row*XSTRIDE + 4 + q*4;
    }

    float  acc[4][6] = {};
    float4 nxt[6];

    // ---- prologue: issue loads for it=0 (ci=0, i=0, j=0) ----
    {
        const float* xp = xg + (size_t)b*18874368
                             + (size_t)c*589824 + (size_t)t*73728;
        #pragma unroll
        for (int p = 0; p < 6; ++p)
            if (pv[p]) nxt[p] = *(const float4*)(xp + goff[p]);
    }

    #pragma unroll 1
    for (int it = 0; it < 36; ++it) {
        int ci = it / 9;
        int ij = it % 9;

        __syncthreads();   // previous iter's readers done before overwrite
        // ---- write staged regs -> LDS (4x b32 per pass; stride-105 rows) ----
        #pragma unroll
        for (int p = 0; p < 6; ++p) {
            if (pv[p]) {
                float4 v = nxt[p];
                xs[lw[p] + 0] = v.x;
                xs[lw[p] + 1] = v.y;
                xs[lw[p] + 2] = v.z;
                xs[lw[p] + 3] = v.w;
            }
        }
        __syncthreads();

        // ---- issue NEXT tile's global loads (in flight during compute) ----
        if (it < 35) {
            int it2 = it + 1;
            int ci2 = it2 / 9;
            int ij2 = it2 % 9;
            int i2  = ij2 / 3;
            int j2  = ij2 % 3;
            const float* xp = xg + (size_t)b*18874368 + (size_t)ci2*4718592
                                 + (size_t)(c + i2)*589824
                                 + (size_t)(t + j2)*73728;
            #pragma unroll
            for (int p = 0; p < 6; ++p)
                if (pv[p]) nxt[p] = *(const float4*)(xp + goff[p]);
        }

        // ---- compute: 9 rows x (3 kw x 6 w x 4 o) = 648 FMAs ----
        // weights: wave-uniform global reads from repacked workspace
        const float4* wq4 = (const float4*)(wsW + (ci*9 + ij)*108);
        #pragma unroll
        for (int pl = 0; pl < 3; ++pl) {
            #pragma unroll
            for (int kh = 0; kh < 3; ++kh) {
                // taps w0-1..w0+6 -> xs idx (w0+3)..(w0+10); bank-parity of the
                // 4 hr-groups alternates (9g mod 32) -> 2 lanes/bank, conflict-free
                const float* xr = &xs[(pl*18 + hr_out + kh)*XSTRIDE + 3 + 6*wt];
                float x0 = xr[0], x1 = xr[1], x2 = xr[2], x3 = xr[3];
                float x4 = xr[4], x5 = xr[5], x6 = xr[6], x7 = xr[7];
                float xv[8] = {x0, x1, x2, x3, x4, x5, x6, x7};
                const float4* wr = wq4 + (pl*3 + kh)*3;
                float4 wk0 = wr[0];
                float4 wk1 = wr[1];
                float4 wk2 = wr[2];
                #pragma unroll
                for (int v = 0; v < 6; ++v) {
                    float a = xv[v], bb = xv[v+1], cc = xv[v+2];
                    acc[0][v] = fmaf(a,  wk0.x, acc[0][v]);
                    acc[1][v] = fmaf(a,  wk0.y, acc[1][v]);
                    acc[2][v] = fmaf(a,  wk0.z, acc[2][v]);
                    acc[3][v] = fmaf(a,  wk0.w, acc[3][v]);
                    acc[0][v] = fmaf(bb, wk1.x, acc[0][v]);
                    acc[1][v] = fmaf(bb, wk1.y, acc[1][v]);
                    acc[2][v] = fmaf(bb, wk1.z, acc[2][v]);
                    acc[3][v] = fmaf(bb, wk1.w, acc[3][v]);
                    acc[0][v] = fmaf(cc, wk2.x, acc[0][v]);
                    acc[1][v] = fmaf(cc, wk2.y, acc[1][v]);
                    acc[2][v] = fmaf(cc, wk2.z, acc[2][v]);
                    acc[3][v] = fmaf(cc, wk2.w, acc[3][v]);
                }
            }
        }
    }

    // mean bias (precomputed by prep_kernel)
    float4 mb4 = *(const float4*)(wsW + 3888);
    float mb[4] = {mb4.x, mb4.y, mb4.z, mb4.w};

    const float inv9 = 1.0f / 9.0f;
    size_t obase = (size_t)b*10616832 + (size_t)c*442368 + (size_t)t*73728
                 + (size_t)d*9216 + (size_t)(h0 + hr_out)*96 + 6*wt;
    #pragma unroll
    for (int o = 0; o < 4; ++o) {
        float* op = outg + obase + (size_t)o*2654208;
        #pragma unroll
        for (int v = 0; v < 3; ++v) {
            float2 st;
            st.x = acc[o][2*v]   * inv9 + mb[o];
            st.y = acc[o][2*v+1] * inv9 + mb[o];
            *(float2*)(op + 2*v) = st;
        }
    }
}

extern "C" void kernel_launch(void* const* d_in, const int* in_sizes, int n_in,
                              void* d_out, int out_size, void* d_ws, size_t ws_size,
                              hipStream_t stream) {
    const float* x = (const float*)d_in[0];
    const float* W = (const float*)d_in[1];
    const float* b = (const float*)d_in[2];
    float* out = (float*)d_out;
    float* ws  = (float*)d_ws;

    prep_kernel<<<16, BLOCK, 0, stream>>>(W, b, ws);
    conv5d_kernel<<<3456, BLOCK, 0, stream>>>(x, ws, out);
}

// Round 2
// 719.085 us; speedup vs baseline: 1.7576x; 1.7576x over previous
//
#include <hip/hip_runtime.h>

// x:   (2,4,8,8,8,96,96) fp32   strides: b 18874368, ci 4718592, cd 589824, t 73728, d 9216, h 96, w 1
// W:   (9,4,4,3,3,3)     fp32   strides: ij 432, o 108, ci 27, kd 9, kh 3, kw 1
// b:   (9,4)             fp32
// out: (2,4,6,6,8,96,96) fp32
//
// Round-2: round-0 loop structure (short-live-range staging) + the validated
// round-1 wins, minus the spill source.
//  - LDS row stride 105 (odd): compute reads are 2 lanes/bank = conflict-free.
//  - weights read from workspace (repacked by prep_kernel) with wave-uniform
//    addresses; LDS holds only the x tile: 22.7 KB -> ~6 blocks/CU.
//  - staging descriptors (goff/lw/pv) precomputed once; halo/invalid rows
//    zeroed once and never re-staged.
//  - NO cross-compute register prefetch (round-1 spilled: VGPR cap 102 vs
//    pressure ~120 -> 3.5 GB scratch traffic). Staging loads live only
//    within the stage phase. __launch_bounds__(256,4): cap 128 VGPRs.

#define BLOCK 256
#define XSTRIDE 105   // odd: (9*hr + 6*wt) mod 32 splits lane groups across bank parity

__global__ void prep_kernel(const float* __restrict__ Wg,
                            const float* __restrict__ bg,
                            float* __restrict__ ws)
{
    int k = blockIdx.x * blockDim.x + threadIdx.x;
    if (k < 3888) {
        int o  = k & 3;  int r = k >> 2;
        int kw = r % 3;  r /= 3;
        int kh = r % 3;  r /= 3;
        int kd = r % 3;  r /= 3;
        int ij = r % 9;  int ci = r / 9;
        ws[k] = Wg[ij*432 + o*108 + ci*27 + kd*9 + kh*3 + kw];
    }
    if (k < 4) {
        float s = 0.f;
        #pragma unroll
        for (int ij = 0; ij < 9; ++ij) s += bg[ij*4 + k];
        ws[3888 + k] = s * (1.0f / 9.0f);
    }
}

__global__ __launch_bounds__(256, 4) void conv5d_kernel(
    const float* __restrict__ xg,
    const float* __restrict__ wsW,
    float* __restrict__ outg)
{
    __shared__ float xs[54 * XSTRIDE];   // [pl(3)][hr(18)][wcol(105)], 22680 B

    // zero once: w-halo cols (idx 3 / 100) and out-of-range d/h rows are
    // never re-staged afterwards.
    for (int k = threadIdx.x; k < 54 * XSTRIDE; k += BLOCK) xs[k] = 0.f;

    // Block decode with XCD-aware swizzle: 3456 blocks = 72 (b,c,t) slabs x
    // 48 (d,ht); each XCD (bi&7) gets 9 contiguous slabs for L2 locality.
    int bi   = blockIdx.x;
    int xcd  = bi & 7;
    int g    = bi >> 3;
    int slab = xcd*9 + g/48;
    int r2   = g % 48;
    int d    = r2 / 6;
    int ht   = r2 % 6;
    int b    = slab / 36;
    int ct   = slab % 36;
    int c    = ct / 6;
    int t    = ct % 6;
    int h0   = ht * 16;

    int wt     = threadIdx.x & 15;   // w tile: w0 = 6*wt
    int hr_out = threadIdx.x >> 4;   // 0..15

    // ---- loop-invariant staging descriptors (6 passes/thread) ----
    int  goff[6];   // float offset within the (ci, c+i, t+j) plane-slab
    int  lw[6];     // LDS word index of first of 4 writes
    bool pv[6];     // this pass writes a valid row
    #pragma unroll
    for (int p = 0; p < 6; ++p) {
        int u   = threadIdx.x + p*BLOCK;   // 0..1535, valid < 1296
        int row = u / 24;                  // 0..53
        int q   = u % 24;
        int pl  = row / 18;
        int hr  = row % 18;
        int dd  = d + pl - 1;
        int hh  = h0 + hr - 1;
        pv[p]   = (u < 1296) && ((unsigned)dd < 8u) && ((unsigned)hh < 96u);
        goff[p] = dd*9216 + hh*96 + q*4;   // garbage if !pv -> never used
        lw[p]   = row*XSTRIDE + 4 + q*4;
    }

    float acc[4][6] = {};

    #pragma unroll 1
    for (int it = 0; it < 36; ++it) {
        int ci = it / 9;
        int ij = it % 9;
        int i  = ij / 3;
        int j  = ij % 3;
        const float* xp = xg + (size_t)b*18874368 + (size_t)ci*4718592
                             + (size_t)(c + i)*589824
                             + (size_t)(t + j)*73728;

        __syncthreads();   // previous iter's readers (and init zero-fill) done

        // ---- stage: issue all 6 global loads, then write to LDS ----
        // (short live range: v[] dies inside this phase -> no spill pressure)
        float4 v[6];
        #pragma unroll
        for (int p = 0; p < 6; ++p)
            if (pv[p]) v[p] = *(const float4*)(xp + goff[p]);
        #pragma unroll
        for (int p = 0; p < 6; ++p) {
            if (pv[p]) {
                xs[lw[p] + 0] = v[p].x;
                xs[lw[p] + 1] = v[p].y;
                xs[lw[p] + 2] = v[p].z;
                xs[lw[p] + 3] = v[p].w;
            }
        }
        __syncthreads();

        // ---- compute: 9 rows x (3 kw x 6 w x 4 o) = 648 FMAs ----
        const float4* wq4 = (const float4*)(wsW + (ci*9 + ij)*108);
        #pragma unroll
        for (int pl = 0; pl < 3; ++pl) {
            #pragma unroll
            for (int kh = 0; kh < 3; ++kh) {
                // taps w0-1..w0+6 -> xs idx (w0+3)..(w0+10); banks
                // (9*row + 6*wt) mod 32: lane groups alternate parity ->
                // 2 lanes/bank = conflict-free
                const float* xr = &xs[(pl*18 + hr_out + kh)*XSTRIDE + 3 + 6*wt];
                float x0 = xr[0], x1 = xr[1], x2 = xr[2], x3 = xr[3];
                float x4 = xr[4], x5 = xr[5], x6 = xr[6], x7 = xr[7];
                float xv[8] = {x0, x1, x2, x3, x4, x5, x6, x7};
                const float4* wr = wq4 + (pl*3 + kh)*3;
                float4 wk0 = wr[0];
                float4 wk1 = wr[1];
                float4 wk2 = wr[2];
                #pragma unroll
                for (int vv = 0; vv < 6; ++vv) {
                    float a = xv[vv], bb = xv[vv+1], cc = xv[vv+2];
                    acc[0][vv] = fmaf(a,  wk0.x, acc[0][vv]);
                    acc[1][vv] = fmaf(a,  wk0.y, acc[1][vv]);
                    acc[2][vv] = fmaf(a,  wk0.z, acc[2][vv]);
                    acc[3][vv] = fmaf(a,  wk0.w, acc[3][vv]);
                    acc[0][vv] = fmaf(bb, wk1.x, acc[0][vv]);
                    acc[1][vv] = fmaf(bb, wk1.y, acc[1][vv]);
                    acc[2][vv] = fmaf(bb, wk1.z, acc[2][vv]);
                    acc[3][vv] = fmaf(bb, wk1.w, acc[3][vv]);
                    acc[0][vv] = fmaf(cc, wk2.x, acc[0][vv]);
                    acc[1][vv] = fmaf(cc, wk2.y, acc[1][vv]);
                    acc[2][vv] = fmaf(cc, wk2.z, acc[2][vv]);
                    acc[3][vv] = fmaf(cc, wk2.w, acc[3][vv]);
                }
            }
        }
    }

    // mean bias (precomputed by prep_kernel)
    float4 mb4 = *(const float4*)(wsW + 3888);
    float mb[4] = {mb4.x, mb4.y, mb4.z, mb4.w};

    const float inv9 = 1.0f / 9.0f;
    size_t obase = (size_t)b*10616832 + (size_t)c*442368 + (size_t)t*73728
                 + (size_t)d*9216 + (size_t)(h0 + hr_out)*96 + 6*wt;
    #pragma unroll
    for (int o = 0; o < 4; ++o) {
        float* op = outg + obase + (size_t)o*2654208;
        #pragma unroll
        for (int vv = 0; vv < 3; ++vv) {
            float2 st;
            st.x = acc[o][2*vv]   * inv9 + mb[o];
            st.y = acc[o][2*vv+1] * inv9 + mb[o];
            *(float2*)(op + 2*vv) = st;
        }
    }
}

extern "C" void kernel_launch(void* const* d_in, const int* in_sizes, int n_in,
                              void* d_out, int out_size, void* d_ws, size_t ws_size,
                              hipStream_t stream) {
    const float* x = (const float*)d_in[0];
    const float* W = (const float*)d_in[1];
    const float* b = (const float*)d_in[2];
    float* out = (float*)d_out;
    float* ws  = (float*)d_ws;

    prep_kernel<<<16, BLOCK, 0, stream>>>(W, b, ws);
    conv5d_kernel<<<3456, BLOCK, 0, stream>>>(x, ws, out);
}

// Round 3
// 699.012 us; speedup vs baseline: 1.8081x; 1.0287x over previous
//
#include <hip/hip_runtime.h>

// x:   (2,4,8,8,8,96,96) fp32   strides: b 18874368, ci 4718592, cd 589824, t 73728, d 9216, h 96, w 1
// W:   (9,4,4,3,3,3)     fp32
// b:   (9,4)             fp32
// out: (2,4,6,6,8,96,96) fp32
//
// Round-3: round-2 pipeline + register prefetch reinstated under a 128-VGPR
// cap. Round-1 proved the prefetch structure correct but spilled at the
// (256,5) 102-VGPR cap (WRITE_SIZE 92MB->2GB). Round-2 base usage is 60
// VGPRs; +24 prefetch regs ~= 90-105 peak, under the (256,4) cap of 128.
//  - LDS row stride 105 (odd): compute reads 2 lanes/bank = conflict-free.
//  - weights from workspace (prep_kernel repack), wave-uniform -> s_load.
//  - staging descriptors precomputed; halo/invalid rows zeroed once.
//  - per iter: sync -> ds_write(prefetched regs) -> sync -> issue next
//    tile's global loads -> 648 FMAs (loads in flight under compute).

#define BLOCK 256
#define XSTRIDE 105

__global__ void prep_kernel(const float* __restrict__ Wg,
                            const float* __restrict__ bg,
                            float* __restrict__ ws)
{
    int k = blockIdx.x * blockDim.x + threadIdx.x;
    if (k < 3888) {
        int o  = k & 3;  int r = k >> 2;
        int kw = r % 3;  r /= 3;
        int kh = r % 3;  r /= 3;
        int kd = r % 3;  r /= 3;
        int ij = r % 9;  int ci = r / 9;
        ws[k] = Wg[ij*432 + o*108 + ci*27 + kd*9 + kh*3 + kw];
    }
    if (k < 4) {
        float s = 0.f;
        #pragma unroll
        for (int ij = 0; ij < 9; ++ij) s += bg[ij*4 + k];
        ws[3888 + k] = s * (1.0f / 9.0f);
    }
}

__global__ __launch_bounds__(256, 4) void conv5d_kernel(
    const float* __restrict__ xg,
    const float* __restrict__ wsW,
    float* __restrict__ outg)
{
    __shared__ float xs[54 * XSTRIDE];   // 22680 B

    for (int k = threadIdx.x; k < 54 * XSTRIDE; k += BLOCK) xs[k] = 0.f;

    // XCD-aware block decode: 3456 blocks = 72 (b,c,t) slabs x 48 (d,ht).
    int bi   = blockIdx.x;
    int xcd  = bi & 7;
    int g    = bi >> 3;
    int slab = xcd*9 + g/48;
    int r2   = g % 48;
    int d    = r2 / 6;
    int ht   = r2 % 6;
    int b    = slab / 36;
    int ct   = slab % 36;
    int c    = ct / 6;
    int t    = ct % 6;
    int h0   = ht * 16;

    int wt     = threadIdx.x & 15;   // w0 = 6*wt
    int hr_out = threadIdx.x >> 4;   // 0..15

    // ---- loop-invariant staging descriptors ----
    int  goff[6];
    int  lw[6];
    bool pv[6];
    #pragma unroll
    for (int p = 0; p < 6; ++p) {
        int u   = threadIdx.x + p*BLOCK;   // valid < 1296
        int row = u / 24;
        int q   = u % 24;
        int pl  = row / 18;
        int hr  = row % 18;
        int dd  = d + pl - 1;
        int hh  = h0 + hr - 1;
        pv[p]   = (u < 1296) && ((unsigned)dd < 8u) && ((unsigned)hh < 96u);
        goff[p] = dd*9216 + hh*96 + q*4;
        lw[p]   = row*XSTRIDE + 4 + q*4;
    }

    float  acc[4][6] = {};
    float4 nxt[6];

    // prologue: loads for it=0 (ci=0,i=0,j=0)
    {
        const float* xp = xg + (size_t)b*18874368
                             + (size_t)c*589824 + (size_t)t*73728;
        #pragma unroll
        for (int p = 0; p < 6; ++p)
            if (pv[p]) nxt[p] = *(const float4*)(xp + goff[p]);
    }

    #pragma unroll 1
    for (int it = 0; it < 36; ++it) {
        int ci = it / 9;
        int ij = it % 9;

        __syncthreads();   // previous iter's readers done before overwrite
        #pragma unroll
        for (int p = 0; p < 6; ++p) {
            if (pv[p]) {
                float4 v = nxt[p];
                xs[lw[p] + 0] = v.x;
                xs[lw[p] + 1] = v.y;
                xs[lw[p] + 2] = v.z;
                xs[lw[p] + 3] = v.w;
            }
        }
        __syncthreads();

        // issue NEXT tile's loads; they complete under the FMA block below
        if (it < 35) {
            int it2 = it + 1;
            int ci2 = it2 / 9;
            int ij2 = it2 % 9;
            int i2  = ij2 / 3;
            int j2  = ij2 % 3;
            const float* xp = xg + (size_t)b*18874368 + (size_t)ci2*4718592
                                 + (size_t)(c + i2)*589824
                                 + (size_t)(t + j2)*73728;
            #pragma unroll
            for (int p = 0; p < 6; ++p)
                if (pv[p]) nxt[p] = *(const float4*)(xp + goff[p]);
        }

        // ---- compute: 648 FMAs ----
        const float4* wq4 = (const float4*)(wsW + (ci*9 + ij)*108);
        #pragma unroll
        for (int pl = 0; pl < 3; ++pl) {
            #pragma unroll
            for (int kh = 0; kh < 3; ++kh) {
                const float* xr = &xs[(pl*18 + hr_out + kh)*XSTRIDE + 3 + 6*wt];
                float x0 = xr[0], x1 = xr[1], x2 = xr[2], x3 = xr[3];
                float x4 = xr[4], x5 = xr[5], x6 = xr[6], x7 = xr[7];
                float xv[8] = {x0, x1, x2, x3, x4, x5, x6, x7};
                const float4* wr = wq4 + (pl*3 + kh)*3;
                float4 wk0 = wr[0];
                float4 wk1 = wr[1];
                float4 wk2 = wr[2];
                #pragma unroll
                for (int vv = 0; vv < 6; ++vv) {
                    float a = xv[vv], bb = xv[vv+1], cc = xv[vv+2];
                    acc[0][vv] = fmaf(a,  wk0.x, acc[0][vv]);
                    acc[1][vv] = fmaf(a,  wk0.y, acc[1][vv]);
                    acc[2][vv] = fmaf(a,  wk0.z, acc[2][vv]);
                    acc[3][vv] = fmaf(a,  wk0.w, acc[3][vv]);
                    acc[0][vv] = fmaf(bb, wk1.x, acc[0][vv]);
                    acc[1][vv] = fmaf(bb, wk1.y, acc[1][vv]);
                    acc[2][vv] = fmaf(bb, wk1.z, acc[2][vv]);
                    acc[3][vv] = fmaf(bb, wk1.w, acc[3][vv]);
                    acc[0][vv] = fmaf(cc, wk2.x, acc[0][vv]);
                    acc[1][vv] = fmaf(cc, wk2.y, acc[1][vv]);
                    acc[2][vv] = fmaf(cc, wk2.z, acc[2][vv]);
                    acc[3][vv] = fmaf(cc, wk2.w, acc[3][vv]);
                }
            }
        }
    }

    float4 mb4 = *(const float4*)(wsW + 3888);
    float mb[4] = {mb4.x, mb4.y, mb4.z, mb4.w};

    const float inv9 = 1.0f / 9.0f;
    size_t obase = (size_t)b*10616832 + (size_t)c*442368 + (size_t)t*73728
                 + (size_t)d*9216 + (size_t)(h0 + hr_out)*96 + 6*wt;
    #pragma unroll
    for (int o = 0; o < 4; ++o) {
        float* op = outg + obase + (size_t)o*2654208;
        #pragma unroll
        for (int vv = 0; vv < 3; ++vv) {
            float2 st;
            st.x = acc[o][2*vv]   * inv9 + mb[o];
            st.y = acc[o][2*vv+1] * inv9 + mb[o];
            *(float2*)(op + 2*vv) = st;
        }
    }
}

extern "C" void kernel_launch(void* const* d_in, const int* in_sizes, int n_in,
                              void* d_out, int out_size, void* d_ws, size_t ws_size,
                              hipStream_t stream) {
    const float* x = (const float*)d_in[0];
    const float* W = (const float*)d_in[1];
    const float* b = (const float*)d_in[2];
    float* out = (float*)d_out;
    float* ws  = (float*)d_ws;

    prep_kernel<<<16, BLOCK, 0, stream>>>(W, b, ws);
    conv5d_kernel<<<3456, BLOCK, 0, stream>>>(x, ws, out);
}